// Round 3
// baseline (194.204 us; speedup 1.0000x reference)
//
#include <hip/hip_runtime.h>

#define DD 128   // drug feature dim
#define HH 32    // hidden dim
#define EPB 256  // edges per block (4 waves x 64)
#define ROWB 40  // bf16 per LDS row (80 B): 16B-aligned b128 reads, 2-way conflicts only

typedef __bf16 bf16x8 __attribute__((ext_vector_type(8)));
typedef float  f32x4  __attribute__((ext_vector_type(4)));

// All four layers on MFMA (16x16x32 bf16). Per 16-edge tile:
//   L1: 8 MFMAs (K=128), L2: 2 (K=32), L3: 2, L4: per-lane dot + 2 shuffles.
// C->A layout transforms go through a per-wave LDS buffer (no __syncthreads:
// each tile is wholly owned by one wave; in-order LDS pipe + lgkmcnt suffice).
// Biases enter via MFMA C-initialization.
__global__ __launch_bounds__(256)
void synergy_mfma_full(const float* __restrict__ drug,   // [N_DRUGS,128]
                       const int*   __restrict__ edges,  // [E,4]
                       const float* __restrict__ W1, const float* __restrict__ b1,
                       const float* __restrict__ W2, const float* __restrict__ b2,
                       const float* __restrict__ W3, const float* __restrict__ b3,
                       const float* __restrict__ W4, const float* __restrict__ b4,
                       float* __restrict__ out, int E)
{
    __shared__ __align__(16) __bf16 hls[4][16 * ROWB];   // 4 x 1280 B = 5120 B

    const int tid  = threadIdx.x;
    const int wave = tid >> 6;
    const int lane = tid & 63;
    const int m    = lane & 15;   // A/C row-group & B col
    const int q    = lane >> 4;   // quad

    __bf16* __restrict__ hb = hls[wave];

    const int blockBase = blockIdx.x * EPB;
    const int waveBase  = blockBase + wave * 64;

    const int4*   __restrict__ edges4 = reinterpret_cast<const int4*>(edges);
    const float4* __restrict__ drug4  = reinterpret_cast<const float4*>(drug);
    const float4* __restrict__ W1v    = reinterpret_cast<const float4*>(W1);
    const float4* __restrict__ W2v    = reinterpret_cast<const float4*>(W2);
    const float4* __restrict__ W3v    = reinterpret_cast<const float4*>(W3);
    const float4* __restrict__ W4v    = reinterpret_cast<const float4*>(W4);

    // ---- Persistent B-fragments: B[k=8q+j][n=16t+m] = W[n][k] ----
    bf16x8 bw1[2][4];                       // W1: K=128 -> 4 k-steps
    #pragma unroll
    for (int t = 0; t < 2; ++t) {
        #pragma unroll
        for (int f = 0; f < 4; ++f) {
            const int c4 = ((t * 16 + m) * DD + f * 32 + q * 8) >> 2;
            const float4 w0 = W1v[c4], w1 = W1v[c4 + 1];
            bw1[t][f][0] = (__bf16)w0.x; bw1[t][f][1] = (__bf16)w0.y;
            bw1[t][f][2] = (__bf16)w0.z; bw1[t][f][3] = (__bf16)w0.w;
            bw1[t][f][4] = (__bf16)w1.x; bw1[t][f][5] = (__bf16)w1.y;
            bw1[t][f][6] = (__bf16)w1.z; bw1[t][f][7] = (__bf16)w1.w;
        }
    }
    bf16x8 bw2[2], bw3[2];                  // W2/W3: K=32 -> 1 k-step
    #pragma unroll
    for (int t = 0; t < 2; ++t) {
        const int c4 = ((t * 16 + m) * HH + q * 8) >> 2;
        float4 w0 = W2v[c4], w1 = W2v[c4 + 1];
        bw2[t][0] = (__bf16)w0.x; bw2[t][1] = (__bf16)w0.y;
        bw2[t][2] = (__bf16)w0.z; bw2[t][3] = (__bf16)w0.w;
        bw2[t][4] = (__bf16)w1.x; bw2[t][5] = (__bf16)w1.y;
        bw2[t][6] = (__bf16)w1.z; bw2[t][7] = (__bf16)w1.w;
        w0 = W3v[c4]; w1 = W3v[c4 + 1];
        bw3[t][0] = (__bf16)w0.x; bw3[t][1] = (__bf16)w0.y;
        bw3[t][2] = (__bf16)w0.z; bw3[t][3] = (__bf16)w0.w;
        bw3[t][4] = (__bf16)w1.x; bw3[t][5] = (__bf16)w1.y;
        bw3[t][6] = (__bf16)w1.z; bw3[t][7] = (__bf16)w1.w;
    }
    const float bias1a = b1[m], bias1b = b1[16 + m];
    const float bias2a = b2[m], bias2b = b2[16 + m];
    const float bias3a = b3[m], bias3b = b3[16 + m];
    float w4s[8];
    {
        const float4 a = W4v[q * 2], b = W4v[q * 2 + 1];
        w4s[0] = a.x; w4s[1] = a.y; w4s[2] = a.z; w4s[3] = a.w;
        w4s[4] = b.x; w4s[5] = b.y; w4s[6] = b.z; w4s[7] = b.w;
    }
    const float b4s = b4[0];

    #pragma unroll
    for (int mt = 0; mt < 4; ++mt) {
        const int eIdx = waveBase + mt * 16 + m;
        const int eCl  = (eIdx < E) ? eIdx : (E - 1);
        const int4 ed  = edges4[eCl];
        const float4* __restrict__ r0 = drug4 + ed.x * (DD / 4);
        const float4* __restrict__ r1 = drug4 + ed.y * (DD / 4);
        const float4* __restrict__ r2 = drug4 + ed.z * (DD / 4);

        // ---- L1: logits @ W1^T + b1 (bias via C-init) ----
        f32x4 acc0 = {bias1a, bias1a, bias1a, bias1a};
        f32x4 acc1 = {bias1b, bias1b, bias1b, bias1b};
        #pragma unroll
        for (int f = 0; f < 4; ++f) {
            const int c4 = f * 8 + q * 2;          // k0 = 32f + 8q
            const float4 a0 = r0[c4], a1 = r0[c4 + 1];
            const float4 d0 = r1[c4], d1 = r1[c4 + 1];
            const float4 c0 = r2[c4], c1 = r2[c4 + 1];
            bf16x8 af;
            af[0] = (__bf16)(a0.x * d0.x * c0.x);
            af[1] = (__bf16)(a0.y * d0.y * c0.y);
            af[2] = (__bf16)(a0.z * d0.z * c0.z);
            af[3] = (__bf16)(a0.w * d0.w * c0.w);
            af[4] = (__bf16)(a1.x * d1.x * c1.x);
            af[5] = (__bf16)(a1.y * d1.y * c1.y);
            af[6] = (__bf16)(a1.z * d1.z * c1.z);
            af[7] = (__bf16)(a1.w * d1.w * c1.w);
            acc0 = __builtin_amdgcn_mfma_f32_16x16x32_bf16(af, bw1[0][f], acc0, 0, 0, 0);
            acc1 = __builtin_amdgcn_mfma_f32_16x16x32_bf16(af, bw1[1][f], acc1, 0, 0, 0);
        }
        // relu -> LDS [edge][k] (C-layout: lane holds rows 4q+r, cols m / m+16)
        #pragma unroll
        for (int r = 0; r < 4; ++r) {
            const int er = 4 * q + r;
            hb[er * ROWB + m]      = (__bf16)fmaxf(acc0[r], 0.0f);
            hb[er * ROWB + 16 + m] = (__bf16)fmaxf(acc1[r], 0.0f);
        }

        // ---- L2 ----
        bf16x8 af2 = *reinterpret_cast<const bf16x8*>(&hb[m * ROWB + q * 8]);
        f32x4 a20 = {bias2a, bias2a, bias2a, bias2a};
        f32x4 a21 = {bias2b, bias2b, bias2b, bias2b};
        a20 = __builtin_amdgcn_mfma_f32_16x16x32_bf16(af2, bw2[0], a20, 0, 0, 0);
        a21 = __builtin_amdgcn_mfma_f32_16x16x32_bf16(af2, bw2[1], a21, 0, 0, 0);
        #pragma unroll
        for (int r = 0; r < 4; ++r) {
            const int er = 4 * q + r;
            hb[er * ROWB + m]      = (__bf16)fmaxf(a20[r], 0.0f);
            hb[er * ROWB + 16 + m] = (__bf16)fmaxf(a21[r], 0.0f);
        }

        // ---- L3 ----
        bf16x8 af3 = *reinterpret_cast<const bf16x8*>(&hb[m * ROWB + q * 8]);
        f32x4 a30 = {bias3a, bias3a, bias3a, bias3a};
        f32x4 a31 = {bias3b, bias3b, bias3b, bias3b};
        a30 = __builtin_amdgcn_mfma_f32_16x16x32_bf16(af3, bw3[0], a30, 0, 0, 0);
        a31 = __builtin_amdgcn_mfma_f32_16x16x32_bf16(af3, bw3[1], a31, 0, 0, 0);
        #pragma unroll
        for (int r = 0; r < 4; ++r) {
            const int er = 4 * q + r;
            hb[er * ROWB + m]      = (__bf16)fmaxf(a30[r], 0.0f);
            hb[er * ROWB + 16 + m] = (__bf16)fmaxf(a31[r], 0.0f);
        }

        // ---- L4: per-lane 8-wide dot on A-layout slice + cross-quad reduce ----
        bf16x8 af4 = *reinterpret_cast<const bf16x8*>(&hb[m * ROWB + q * 8]);
        float zz = 0.0f;
        #pragma unroll
        for (int j = 0; j < 8; ++j) zz = fmaf((float)af4[j], w4s[j], zz);
        zz += __shfl_xor(zz, 16, 64);
        zz += __shfl_xor(zz, 32, 64);
        const float x = 1.0f / (1.0f + __expf(-(zz + b4s)));
        if (q == 0 && eIdx < E) out[eIdx] = x;
    }

    // ---- labels, coalesced pass-through ----
    const int e = blockBase + tid;
    if (e < E) out[E + e] = (float)edges4[e].w;
}

extern "C" void kernel_launch(void* const* d_in, const int* in_sizes, int n_in,
                              void* d_out, int out_size, void* d_ws, size_t ws_size,
                              hipStream_t stream)
{
    const float* drug  = (const float*)d_in[0];
    // d_in[1] (cell_hidden_out), d_in[3] (proj_W), d_in[4] (proj_b): dead code
    const int*   edges = (const int*)d_in[2];
    const float* W1 = (const float*)d_in[5];
    const float* b1 = (const float*)d_in[6];
    const float* W2 = (const float*)d_in[7];
    const float* b2 = (const float*)d_in[8];
    const float* W3 = (const float*)d_in[9];
    const float* b3 = (const float*)d_in[10];
    const float* W4 = (const float*)d_in[11];
    const float* b4 = (const float*)d_in[12];
    float* out = (float*)d_out;

    const int E = in_sizes[2] / 4;
    dim3 block(256);
    dim3 grid((E + EPB - 1) / EPB);
    hipLaunchKernelGGL(synergy_mfma_full, grid, block, 0, stream,
                       drug, edges, W1, b1, W2, b2, W3, b3, W4, b4, out, E);
}

// Round 4
// 156.156 us; speedup vs baseline: 1.2437x; 1.2437x over previous
//
#include <hip/hip_runtime.h>

#define DD 128            // drug feature dim
#define HH 32             // hidden dim
#define EPB 256           // edges per block (4 waves x 64)
#define NT 4              // 16-edge tiles per wave
#define RS 40             // f16 per LDS row (80 B = 20 dwords): conflict-optimal for b128
#define TABQ (4096 * DD / 4)   // float4 count of drug table

typedef _Float16 f16;
typedef _Float16 f16x4 __attribute__((ext_vector_type(4)));
typedef _Float16 f16x8 __attribute__((ext_vector_type(8)));
typedef float    f32x4 __attribute__((ext_vector_type(4)));

// Pre-pass: drug table f32 -> f16 into workspace; label pass-through to out[E..2E).
__global__ __launch_bounds__(256)
void synergy_prepass(const float* __restrict__ drug, const int* __restrict__ edges,
                     f16* __restrict__ tab, float* __restrict__ out, int E)
{
    const int i = blockIdx.x * blockDim.x + threadIdx.x;
    if (i < TABQ) {
        const float4 v = reinterpret_cast<const float4*>(drug)[i];
        f16x4 h;
        h[0] = (f16)v.x; h[1] = (f16)v.y; h[2] = (f16)v.z; h[3] = (f16)v.w;
        reinterpret_cast<f16x4*>(tab)[i] = h;
    }
    if (i < E) out[E + i] = (float)edges[4 * i + 3];
}

// Main: all 4 layers on MFMA f16 16x16x32, layer-phased over 4 tiles per wave.
// Gathers read the f16 table (half the lines of f32); products are v_pk_mul_f16
// feeding A-fragments directly. Per-wave LDS buffer, no __syncthreads needed.
__global__ __launch_bounds__(256)
void synergy_main(const f16* __restrict__ tab,    // [4096,128] f16
                  const int* __restrict__ edges,  // [E,4] int32
                  const float* __restrict__ W1, const float* __restrict__ b1,
                  const float* __restrict__ W2, const float* __restrict__ b2,
                  const float* __restrict__ W3, const float* __restrict__ b3,
                  const float* __restrict__ W4, const float* __restrict__ b4,
                  float* __restrict__ out, int E)
{
    __shared__ __align__(16) f16 hls[4][64 * RS];   // 4 waves x 64 rows x 80 B = 20480 B

    const int tid  = threadIdx.x;
    const int wave = tid >> 6;
    const int lane = tid & 63;
    const int m    = lane & 15;   // A row / B col / C col
    const int q    = lane >> 4;   // quad

    f16* __restrict__ hb = hls[wave];
    const int waveBase = blockIdx.x * EPB + wave * 64;

    const int4*  __restrict__ edges4 = reinterpret_cast<const int4*>(edges);
    const f16x8* __restrict__ tabv   = reinterpret_cast<const f16x8*>(tab);
    const float4* __restrict__ W1v   = reinterpret_cast<const float4*>(W1);
    const float4* __restrict__ W2v   = reinterpret_cast<const float4*>(W2);
    const float4* __restrict__ W3v   = reinterpret_cast<const float4*>(W3);
    const float4* __restrict__ W4v   = reinterpret_cast<const float4*>(W4);

    // ---- Persistent f16 B-fragments: B[k=8q+j][n=16t+m] = W[n][k] ----
    f16x8 bw1[2][4];
    #pragma unroll
    for (int t = 0; t < 2; ++t)
        #pragma unroll
        for (int f = 0; f < 4; ++f) {
            const int c4 = ((t * 16 + m) * DD + f * 32 + q * 8) >> 2;
            const float4 w0 = W1v[c4], w1 = W1v[c4 + 1];
            f16x8 r;
            r[0] = (f16)w0.x; r[1] = (f16)w0.y; r[2] = (f16)w0.z; r[3] = (f16)w0.w;
            r[4] = (f16)w1.x; r[5] = (f16)w1.y; r[6] = (f16)w1.z; r[7] = (f16)w1.w;
            bw1[t][f] = r;
        }
    f16x8 bw2[2], bw3[2];
    #pragma unroll
    for (int t = 0; t < 2; ++t) {
        const int c4 = ((t * 16 + m) * HH + q * 8) >> 2;
        float4 w0 = W2v[c4], w1 = W2v[c4 + 1];
        f16x8 r;
        r[0] = (f16)w0.x; r[1] = (f16)w0.y; r[2] = (f16)w0.z; r[3] = (f16)w0.w;
        r[4] = (f16)w1.x; r[5] = (f16)w1.y; r[6] = (f16)w1.z; r[7] = (f16)w1.w;
        bw2[t] = r;
        w0 = W3v[c4]; w1 = W3v[c4 + 1];
        r[0] = (f16)w0.x; r[1] = (f16)w0.y; r[2] = (f16)w0.z; r[3] = (f16)w0.w;
        r[4] = (f16)w1.x; r[5] = (f16)w1.y; r[6] = (f16)w1.z; r[7] = (f16)w1.w;
        bw3[t] = r;
    }
    const float bias1a = b1[m], bias1b = b1[16 + m];
    const float bias2a = b2[m], bias2b = b2[16 + m];
    const float bias3a = b3[m], bias3b = b3[16 + m];
    float w4s[8];
    {
        const float4 a = W4v[q * 2], b = W4v[q * 2 + 1];
        w4s[0] = a.x; w4s[1] = a.y; w4s[2] = a.z; w4s[3] = a.w;
        w4s[4] = b.x; w4s[5] = b.y; w4s[6] = b.z; w4s[7] = b.w;
    }
    const float b4s = b4[0];

    // ---- Hoist edge indices / row offsets for all 4 tiles ----
    int off0[NT], off1[NT], off2[NT];
    #pragma unroll
    for (int t = 0; t < NT; ++t) {
        const int eIdx = waveBase + t * 16 + m;
        const int4 ed  = edges4[(eIdx < E) ? eIdx : (E - 1)];
        off0[t] = ed.x * (DD / 8);   // f16x8 units per row
        off1[t] = ed.y * (DD / 8);
        off2[t] = ed.z * (DD / 8);
    }

    // ---- Phase A: L1 for all 4 tiles (gathers batched per tile, pipeline across t) ----
    #pragma unroll
    for (int t = 0; t < NT; ++t) {
        f16x8 l0[4], l1[4], l2[4];
        #pragma unroll
        for (int f = 0; f < 4; ++f) {
            const int o = f * 4 + q;
            l0[f] = tabv[off0[t] + o];
            l1[f] = tabv[off1[t] + o];
            l2[f] = tabv[off2[t] + o];
        }
        f32x4 acc0 = {bias1a, bias1a, bias1a, bias1a};
        f32x4 acc1 = {bias1b, bias1b, bias1b, bias1b};
        #pragma unroll
        for (int f = 0; f < 4; ++f) {
            const f16x8 p = l0[f] * l1[f] * l2[f];   // v_pk_mul_f16 x8 -> A-fragment
            acc0 = __builtin_amdgcn_mfma_f32_16x16x32_f16(p, bw1[0][f], acc0, 0, 0, 0);
            acc1 = __builtin_amdgcn_mfma_f32_16x16x32_f16(p, bw1[1][f], acc1, 0, 0, 0);
        }
        #pragma unroll
        for (int r = 0; r < 4; ++r) {
            const int row = t * 16 + 4 * q + r;
            hb[row * RS + m]      = (f16)fmaxf(acc0[r], 0.0f);
            hb[row * RS + 16 + m] = (f16)fmaxf(acc1[r], 0.0f);
        }
    }

    // ---- Phase B: L2 ----
    #pragma unroll
    for (int t = 0; t < NT; ++t) {
        const f16x8 a = *reinterpret_cast<const f16x8*>(&hb[(t * 16 + m) * RS + q * 8]);
        f32x4 c0 = {bias2a, bias2a, bias2a, bias2a};
        f32x4 c1 = {bias2b, bias2b, bias2b, bias2b};
        c0 = __builtin_amdgcn_mfma_f32_16x16x32_f16(a, bw2[0], c0, 0, 0, 0);
        c1 = __builtin_amdgcn_mfma_f32_16x16x32_f16(a, bw2[1], c1, 0, 0, 0);
        #pragma unroll
        for (int r = 0; r < 4; ++r) {
            const int row = t * 16 + 4 * q + r;
            hb[row * RS + m]      = (f16)fmaxf(c0[r], 0.0f);
            hb[row * RS + 16 + m] = (f16)fmaxf(c1[r], 0.0f);
        }
    }

    // ---- Phase C: L3 ----
    #pragma unroll
    for (int t = 0; t < NT; ++t) {
        const f16x8 a = *reinterpret_cast<const f16x8*>(&hb[(t * 16 + m) * RS + q * 8]);
        f32x4 c0 = {bias3a, bias3a, bias3a, bias3a};
        f32x4 c1 = {bias3b, bias3b, bias3b, bias3b};
        c0 = __builtin_amdgcn_mfma_f32_16x16x32_f16(a, bw3[0], c0, 0, 0, 0);
        c1 = __builtin_amdgcn_mfma_f32_16x16x32_f16(a, bw3[1], c1, 0, 0, 0);
        #pragma unroll
        for (int r = 0; r < 4; ++r) {
            const int row = t * 16 + 4 * q + r;
            hb[row * RS + m]      = (f16)fmaxf(c0[r], 0.0f);
            hb[row * RS + 16 + m] = (f16)fmaxf(c1[r], 0.0f);
        }
    }

    // ---- Phase D: L4 dot + cross-quad reduce + sigmoid + store ----
    #pragma unroll
    for (int t = 0; t < NT; ++t) {
        const f16x8 a = *reinterpret_cast<const f16x8*>(&hb[(t * 16 + m) * RS + q * 8]);
        float z = 0.0f;
        #pragma unroll
        for (int j = 0; j < 8; ++j) z = fmaf((float)a[j], w4s[j], z);
        z += __shfl_xor(z, 16, 64);
        z += __shfl_xor(z, 32, 64);
        const int eIdx = waveBase + t * 16 + m;
        if (q == 0 && eIdx < E)
            out[eIdx] = 1.0f / (1.0f + __expf(-(z + b4s)));
    }
}

extern "C" void kernel_launch(void* const* d_in, const int* in_sizes, int n_in,
                              void* d_out, int out_size, void* d_ws, size_t ws_size,
                              hipStream_t stream)
{
    const float* drug  = (const float*)d_in[0];
    // d_in[1] (cell_hidden_out), d_in[3] (proj_W), d_in[4] (proj_b): dead code
    const int*   edges = (const int*)d_in[2];
    const float* W1 = (const float*)d_in[5];
    const float* b1 = (const float*)d_in[6];
    const float* W2 = (const float*)d_in[7];
    const float* b2 = (const float*)d_in[8];
    const float* W3 = (const float*)d_in[9];
    const float* b3 = (const float*)d_in[10];
    const float* W4 = (const float*)d_in[11];
    const float* b4 = (const float*)d_in[12];
    float* out = (float*)d_out;
    f16*   tab = (f16*)d_ws;    // 4096*128*2 B = 1 MiB of workspace

    const int E = in_sizes[2] / 4;

    const int preN = (E > TABQ) ? E : TABQ;
    hipLaunchKernelGGL(synergy_prepass, dim3((preN + 255) / 256), dim3(256), 0, stream,
                       drug, edges, tab, out, E);
    hipLaunchKernelGGL(synergy_main, dim3((E + EPB - 1) / EPB), dim3(256), 0, stream,
                       tab, edges, W1, b1, W2, b2, W3, b3, W4, b4, out, E);
}

// Round 5
// 147.525 us; speedup vs baseline: 1.3164x; 1.0585x over previous
//
#include <hip/hip_runtime.h>

#define DD 128            // drug feature dim
#define HH 32             // hidden dim
#define NT 2              // 16-edge tiles per wave
#define EPB 128           // edges per block = 4 waves * NT*16
#define RS 40             // f16 per h row (80 B): conflict-free b128 column reads
#define TABQ (4096 * DD / 4)   // float4 count of drug table

typedef _Float16 f16;
typedef _Float16 f16x4 __attribute__((ext_vector_type(4)));
typedef _Float16 f16x8 __attribute__((ext_vector_type(8)));
typedef float    f32x4 __attribute__((ext_vector_type(4)));

// Pre-pass: drug table f32 -> f16 into workspace; label pass-through to out[E..2E).
__global__ __launch_bounds__(256)
void synergy_prepass(const float* __restrict__ drug, const int* __restrict__ edges,
                     f16* __restrict__ tab, float* __restrict__ out, int E)
{
    const int i = blockIdx.x * blockDim.x + threadIdx.x;
    if (i < TABQ) {
        const float4 v = reinterpret_cast<const float4*>(drug)[i];
        f16x4 h;
        h[0] = (f16)v.x; h[1] = (f16)v.y; h[2] = (f16)v.z; h[3] = (f16)v.w;
        reinterpret_cast<f16x4*>(tab)[i] = h;
    }
    if (i < E) out[E + i] = (float)edges[4 * i + 3];
}

// Main: all 4 layers on MFMA f16 16x16x32. ALL weights live in LDS as
// pre-swizzled B-fragments (cooperative preamble, one copy per block) so
// per-wave VGPR stays <= 64 -> 8 waves/SIMD for latency hiding of the
// scattered table gather. Per-wave h-buffer; one __syncthreads (preamble).
__global__ __launch_bounds__(256, 8)
void synergy_main(const f16* __restrict__ tab,    // [4096,128] f16
                  const int* __restrict__ edges,  // [E,4] int32
                  const float* __restrict__ W1, const float* __restrict__ b1,
                  const float* __restrict__ W2, const float* __restrict__ b2,
                  const float* __restrict__ W3, const float* __restrict__ b3,
                  const float* __restrict__ W4, const float* __restrict__ b4,
                  float* __restrict__ out, int E)
{
    // LDS: 8192 + 2*2048 + 64 + 388 + 10240 = 22980 B -> 6 blocks/CU
    __shared__ __align__(16) f16 w1f[2][4][64 * 8];  // [n-half][kstep][lane*8]
    __shared__ __align__(16) f16 w2f[2][64 * 8];
    __shared__ __align__(16) f16 w3f[2][64 * 8];
    __shared__ __align__(16) f16 w4f[4 * 8];         // [q][8]
    __shared__ float bls[3][32];
    __shared__ float b4ls;
    __shared__ __align__(16) f16 hls[4][NT * 16 * RS];   // per-wave h rows

    const int tid  = threadIdx.x;
    const int wave = tid >> 6;
    const int lane = tid & 63;
    const int m    = lane & 15;   // A row / B col / C col
    const int q    = lane >> 4;   // quad

    const float4* __restrict__ W1v = reinterpret_cast<const float4*>(W1);
    const float4* __restrict__ W2v = reinterpret_cast<const float4*>(W2);
    const float4* __restrict__ W3v = reinterpret_cast<const float4*>(W3);
    const float4* __restrict__ W4v = reinterpret_cast<const float4*>(W4);

    // ---- Cooperative weight preamble: fragment layout B[k=8q+j][n=16t+m] = W[n][k]
    #pragma unroll
    for (int it = 0; it < 2; ++it) {            // W1: 512 x 16B blocks
        const int B  = it * 256 + tid;
        const int t  = B >> 8, f = (B >> 6) & 3, l = B & 63;
        const int mm = l & 15, qq = l >> 4;
        const int c4 = (t * 16 + mm) * (DD / 4) + f * 8 + qq * 2;
        const float4 w0 = W1v[c4], w1 = W1v[c4 + 1];
        f16x8 r;
        r[0] = (f16)w0.x; r[1] = (f16)w0.y; r[2] = (f16)w0.z; r[3] = (f16)w0.w;
        r[4] = (f16)w1.x; r[5] = (f16)w1.y; r[6] = (f16)w1.z; r[7] = (f16)w1.w;
        *reinterpret_cast<f16x8*>(&w1f[t][f][l * 8]) = r;
    }
    {                                            // W2 (tid<128) / W3 (tid>=128)
        const int B  = tid & 127;
        const int t  = B >> 6, l = B & 63;
        const int mm = l & 15, qq = l >> 4;
        const int c4 = (t * 16 + mm) * (HH / 4) + qq * 2;
        const float4* __restrict__ src = (tid < 128) ? W2v : W3v;
        const float4 w0 = src[c4], w1 = src[c4 + 1];
        f16x8 r;
        r[0] = (f16)w0.x; r[1] = (f16)w0.y; r[2] = (f16)w0.z; r[3] = (f16)w0.w;
        r[4] = (f16)w1.x; r[5] = (f16)w1.y; r[6] = (f16)w1.z; r[7] = (f16)w1.w;
        f16* dst = (tid < 128) ? &w2f[t][l * 8] : &w3f[t][l * 8];
        *reinterpret_cast<f16x8*>(dst) = r;
    }
    if (tid < 4) {                               // W4 fragments [q][8]
        const float4 a = W4v[tid * 2], b = W4v[tid * 2 + 1];
        f16x8 r;
        r[0] = (f16)a.x; r[1] = (f16)a.y; r[2] = (f16)a.z; r[3] = (f16)a.w;
        r[4] = (f16)b.x; r[5] = (f16)b.y; r[6] = (f16)b.z; r[7] = (f16)b.w;
        *reinterpret_cast<f16x8*>(&w4f[tid * 8]) = r;
    }
    if (tid < 32)       bls[0][tid]      = b1[tid];
    else if (tid < 64)  bls[1][tid - 32] = b2[tid - 32];
    else if (tid < 96)  bls[2][tid - 64] = b3[tid - 64];
    else if (tid == 96) b4ls = b4[0];
    __syncthreads();

    f16* __restrict__ hb = hls[wave];
    const int waveBase = blockIdx.x * EPB + wave * (NT * 16);
    const int4*  __restrict__ edges4 = reinterpret_cast<const int4*>(edges);
    const f16x8* __restrict__ tabv   = reinterpret_cast<const f16x8*>(tab);

    // ---- Phase A: gather + L1 ----
    {
        const float ba0 = bls[0][m], ba1 = bls[0][16 + m];
        #pragma unroll
        for (int t = 0; t < NT; ++t) {
            const int eIdx = waveBase + t * 16 + m;
            const int4 ed  = edges4[(eIdx < E) ? eIdx : (E - 1)];
            const int o0 = ed.x * (DD / 8);
            const int o1 = ed.y * (DD / 8);
            const int o2 = ed.z * (DD / 8);
            f32x4 acc0 = {ba0, ba0, ba0, ba0};
            f32x4 acc1 = {ba1, ba1, ba1, ba1};
            #pragma unroll
            for (int f = 0; f < 4; ++f) {
                const int o = f * 4 + q;
                const f16x8 p = tabv[o0 + o] * tabv[o1 + o] * tabv[o2 + o];
                const f16x8 wa = *reinterpret_cast<const f16x8*>(&w1f[0][f][lane * 8]);
                const f16x8 wb = *reinterpret_cast<const f16x8*>(&w1f[1][f][lane * 8]);
                acc0 = __builtin_amdgcn_mfma_f32_16x16x32_f16(p, wa, acc0, 0, 0, 0);
                acc1 = __builtin_amdgcn_mfma_f32_16x16x32_f16(p, wb, acc1, 0, 0, 0);
            }
            #pragma unroll
            for (int r = 0; r < 4; ++r) {
                const int row = t * 16 + 4 * q + r;
                hb[row * RS + m]      = (f16)fmaxf(acc0[r], 0.0f);
                hb[row * RS + 16 + m] = (f16)fmaxf(acc1[r], 0.0f);
            }
        }
    }

    // ---- Phase B: L2 ----
    {
        const float bb0 = bls[1][m], bb1 = bls[1][16 + m];
        const f16x8 wa = *reinterpret_cast<const f16x8*>(&w2f[0][lane * 8]);
        const f16x8 wb = *reinterpret_cast<const f16x8*>(&w2f[1][lane * 8]);
        #pragma unroll
        for (int t = 0; t < NT; ++t) {
            const f16x8 a = *reinterpret_cast<const f16x8*>(&hb[(t * 16 + m) * RS + q * 8]);
            f32x4 c0 = {bb0, bb0, bb0, bb0};
            f32x4 c1 = {bb1, bb1, bb1, bb1};
            c0 = __builtin_amdgcn_mfma_f32_16x16x32_f16(a, wa, c0, 0, 0, 0);
            c1 = __builtin_amdgcn_mfma_f32_16x16x32_f16(a, wb, c1, 0, 0, 0);
            #pragma unroll
            for (int r = 0; r < 4; ++r) {
                const int row = t * 16 + 4 * q + r;
                hb[row * RS + m]      = (f16)fmaxf(c0[r], 0.0f);
                hb[row * RS + 16 + m] = (f16)fmaxf(c1[r], 0.0f);
            }
        }
    }

    // ---- Phase C: L3 ----
    {
        const float bc0 = bls[2][m], bc1 = bls[2][16 + m];
        const f16x8 wa = *reinterpret_cast<const f16x8*>(&w3f[0][lane * 8]);
        const f16x8 wb = *reinterpret_cast<const f16x8*>(&w3f[1][lane * 8]);
        #pragma unroll
        for (int t = 0; t < NT; ++t) {
            const f16x8 a = *reinterpret_cast<const f16x8*>(&hb[(t * 16 + m) * RS + q * 8]);
            f32x4 c0 = {bc0, bc0, bc0, bc0};
            f32x4 c1 = {bc1, bc1, bc1, bc1};
            c0 = __builtin_amdgcn_mfma_f32_16x16x32_f16(a, wa, c0, 0, 0, 0);
            c1 = __builtin_amdgcn_mfma_f32_16x16x32_f16(a, wb, c1, 0, 0, 0);
            #pragma unroll
            for (int r = 0; r < 4; ++r) {
                const int row = t * 16 + 4 * q + r;
                hb[row * RS + m]      = (f16)fmaxf(c0[r], 0.0f);
                hb[row * RS + 16 + m] = (f16)fmaxf(c1[r], 0.0f);
            }
        }
    }

    // ---- Phase D: L4 dot + cross-quad reduce + sigmoid + store ----
    {
        const f16x8 w4v = *reinterpret_cast<const f16x8*>(&w4f[q * 8]);
        const float bz = b4ls;
        #pragma unroll
        for (int t = 0; t < NT; ++t) {
            const f16x8 a = *reinterpret_cast<const f16x8*>(&hb[(t * 16 + m) * RS + q * 8]);
            float z = 0.0f;
            #pragma unroll
            for (int j = 0; j < 8; ++j) z = fmaf((float)a[j], (float)w4v[j], z);
            z += __shfl_xor(z, 16, 64);
            z += __shfl_xor(z, 32, 64);
            const int eIdx = waveBase + t * 16 + m;
            if (q == 0 && eIdx < E)
                out[eIdx] = 1.0f / (1.0f + __expf(-(z + bz)));
        }
    }
}

extern "C" void kernel_launch(void* const* d_in, const int* in_sizes, int n_in,
                              void* d_out, int out_size, void* d_ws, size_t ws_size,
                              hipStream_t stream)
{
    const float* drug  = (const float*)d_in[0];
    // d_in[1] (cell_hidden_out), d_in[3] (proj_W), d_in[4] (proj_b): dead code
    const int*   edges = (const int*)d_in[2];
    const float* W1 = (const float*)d_in[5];
    const float* b1 = (const float*)d_in[6];
    const float* W2 = (const float*)d_in[7];
    const float* b2 = (const float*)d_in[8];
    const float* W3 = (const float*)d_in[9];
    const float* b3 = (const float*)d_in[10];
    const float* W4 = (const float*)d_in[11];
    const float* b4 = (const float*)d_in[12];
    float* out = (float*)d_out;
    f16*   tab = (f16*)d_ws;    // 4096*128*2 B = 1 MiB of workspace

    const int E = in_sizes[2] / 4;

    const int preN = (E > TABQ) ? E : TABQ;
    hipLaunchKernelGGL(synergy_prepass, dim3((preN + 255) / 256), dim3(256), 0, stream,
                       drug, edges, tab, out, E);
    hipLaunchKernelGGL(synergy_main, dim3((E + EPB - 1) / EPB), dim3(256), 0, stream,
                       tab, edges, W1, b1, W2, b2, W3, b3, W4, b4, out, E);
}

// Round 6
// 135.940 us; speedup vs baseline: 1.4286x; 1.0852x over previous
//
#include <hip/hip_runtime.h>
#include <stdint.h>

#define DD 128                 // drug feature dim
#define HH 32                  // hidden dim
#define RS 40                  // f16 per h-row (80 B): conflict-free b128 column reads
#define TABQ (4096 * DD / 4)   // float4 count of drug table
#define BLOB_OFF (1u << 20)    // weight fragment blob offset inside d_ws (bytes)

typedef _Float16 f16;
typedef _Float16 f16x4 __attribute__((ext_vector_type(4)));
typedef _Float16 f16x8 __attribute__((ext_vector_type(8)));
typedef float    f32x4 __attribute__((ext_vector_type(4)));

#define GL1(p)  ((const __attribute__((address_space(1))) void*)(p))
#define LDS3(p) ((__attribute__((address_space(3))) void*)(p))

// Pre-pass: (a) drug table f32->f16; (b) labels; (c) weight-fragment blob
// (W1/W2/W3 pre-swizzled into MFMA B-fragment lane order) at ws+1MB.
__global__ __launch_bounds__(256)
void synergy_prepass(const float* __restrict__ drug, const int* __restrict__ edges,
                     const float* __restrict__ W1, const float* __restrict__ W2,
                     const float* __restrict__ W3,
                     f16* __restrict__ tab, float* __restrict__ out, int E, int wBlock)
{
    const int tid = threadIdx.x;
    if ((int)blockIdx.x == wBlock) {
        f16x8* __restrict__ blob16 = (f16x8*)((char*)tab + BLOB_OFF);
        const float4* __restrict__ W1v = (const float4*)W1;
        // W1 -> slots 0..511 : S = t*256 + f*64 + lane ; frag B[k=8q+j][n=16t+m]=W1[n][k]
        #pragma unroll
        for (int p = 0; p < 2; ++p) {
            const int S = p * 256 + tid;
            const int t = S >> 8, f = (S >> 6) & 3, l = S & 63;
            const int mm = l & 15, qq = l >> 4;
            const int c4 = (t * 16 + mm) * (DD / 4) + f * 8 + qq * 2;
            const float4 w0 = W1v[c4], w1 = W1v[c4 + 1];
            f16x8 r;
            r[0]=(f16)w0.x; r[1]=(f16)w0.y; r[2]=(f16)w0.z; r[3]=(f16)w0.w;
            r[4]=(f16)w1.x; r[5]=(f16)w1.y; r[6]=(f16)w1.z; r[7]=(f16)w1.w;
            blob16[S] = r;
        }
        // W2 -> slots 512..639 ; W3 -> slots 640..767
        {
            const int B = tid & 127;
            const int t = B >> 6, l = B & 63;
            const int mm = l & 15, qq = l >> 4;
            const int c4 = (t * 16 + mm) * (HH / 4) + qq * 2;
            const float4* __restrict__ src = (tid < 128) ? (const float4*)W2 : (const float4*)W3;
            const float4 w0 = src[c4], w1 = src[c4 + 1];
            f16x8 r;
            r[0]=(f16)w0.x; r[1]=(f16)w0.y; r[2]=(f16)w0.z; r[3]=(f16)w0.w;
            r[4]=(f16)w1.x; r[5]=(f16)w1.y; r[6]=(f16)w1.z; r[7]=(f16)w1.w;
            blob16[512 + (tid & 128) + B] = r;
        }
        return;
    }
    const int i = blockIdx.x * 256 + tid;
    if (i < TABQ) {
        const float4 v = ((const float4*)drug)[i];
        f16x4 h;
        h[0]=(f16)v.x; h[1]=(f16)v.y; h[2]=(f16)v.z; h[3]=(f16)v.w;
        ((f16x4*)tab)[i] = h;
    }
    if (i < E) out[E + i] = (float)edges[4 * i + 3];
}

// Main: each wave owns 16 edges. 12 global_load_lds DMAs stage the 48 table
// rows (full 256B rows, rotation-swizzled) -> ~96 cache-line transactions in
// flight per wave with zero VGPR cost. Weight fragments DMA'd per block from
// the pre-swizzled blob. 4 layers on MFMA f16 16x16x32; L4 via shuffle-reduce.
__global__ __launch_bounds__(256, 2)
void synergy_main(const f16* __restrict__ tab, const int* __restrict__ edges,
                  const float* __restrict__ W4, const float* __restrict__ b1,
                  const float* __restrict__ b2, const float* __restrict__ b3,
                  const float* __restrict__ b4, float* __restrict__ out, int E)
{
    __shared__ __align__(16) f16 wblob[6144];        // 12288 B: W1/W2/W3 fragments
    __shared__ __align__(16) f16 stage[4][6144];     // 12288 B per wave: 48 rows x 256B

    const int tid  = threadIdx.x;
    const int wave = tid >> 6;
    const int lane = tid & 63;
    const int m    = lane & 15;    // MFMA row / staging slot-in-row
    const int q    = lane >> 4;    // MFMA quad / staging row-in-group

    const int waveBase = blockIdx.x * 64 + wave * 16;

    // ---- pre-barrier global loads: edge indices + biases + W4 column
    int idx[12];
    #pragma unroll
    for (int s = 0; s < 12; ++s) {
        const int t = s >> 2, g = s & 3;
        int e = waveBase + 4 * g + q;
        e = (e < E) ? e : (E - 1);
        idx[s] = edges[e * 4 + t];
    }
    const float b1a = b1[m], b1b = b1[16 + m];
    const float b2a = b2[m], b2b = b2[16 + m];
    const float b3a = b3[m], b3b = b3[16 + m];
    const float w4a = W4[m], w4b = W4[16 + m];
    const float b4v = b4[0];

    // ---- weight blob DMA (block-cooperative: 12 x 1KB wave-instructions)
    const char* __restrict__ tabB = (const char*)tab;
    for (int s = wave; s < 12; s += 4)
        __builtin_amdgcn_global_load_lds(GL1(tabB + BLOB_OFF + s * 1024 + lane * 16),
                                         LDS3((char*)wblob + s * 1024), 16, 0, 0);
    __syncthreads();   // drains weight DMA + all pre-barrier loads (vmcnt(0))

    // ---- W1 fragments LDS->VGPR (ready post-barrier)
    const f16x8* __restrict__ blobL = (const f16x8*)wblob;
    f16x8 wa[2][4];
    #pragma unroll
    for (int t = 0; t < 2; ++t)
        #pragma unroll
        for (int f = 0; f < 4; ++f)
            wa[t][f] = blobL[(t * 4 + f) * 64 + lane];

    // ---- gather DMA: 12 instrs, each stages 4 full rows (rotation swizzle:
    //      row e stores seg (j+e)&15 at slot j -> conflict-clean readback)
    f16* __restrict__ stg = stage[wave];
    #pragma unroll
    for (int s = 0; s < 12; ++s) {
        const int t = s >> 2, g = s & 3;
        const int e_t = 4 * g + q;            // edge-in-tile this lane stages
        const int seg = (m + e_t) & 15;       // rotated segment to fetch
        __builtin_amdgcn_global_load_lds(GL1(tabB + (size_t)((idx[s] << 8) + (seg << 4))),
                                         LDS3((char*)stg + (t * 16 + 4 * g) * 256), 16, 0, 0);
    }
    __builtin_amdgcn_sched_barrier(0);
    __builtin_amdgcn_s_waitcnt(0x0F70);       // vmcnt(0): all 12 DMAs landed
    __builtin_amdgcn_sched_barrier(0);

    // ---- Phase A: L1 (8 MFMAs, K=128)
    f32x4 acc0 = {b1a, b1a, b1a, b1a};
    f32x4 acc1 = {b1b, b1b, b1b, b1b};
    #pragma unroll
    for (int f = 0; f < 4; ++f) {
        const int slot = (((f * 4 + q) - m) & 15) << 3;     // f16 offset of 16B seg
        const f16x8 v0 = *(const f16x8*)(stg + (0 * 16 + m) * 128 + slot);
        const f16x8 v1 = *(const f16x8*)(stg + (1 * 16 + m) * 128 + slot);
        const f16x8 v2 = *(const f16x8*)(stg + (2 * 16 + m) * 128 + slot);
        const f16x8 p = v0 * v1 * v2;                       // v_pk_mul_f16 -> A-frag
        acc0 = __builtin_amdgcn_mfma_f32_16x16x32_f16(p, wa[0][f], acc0, 0, 0, 0);
        acc1 = __builtin_amdgcn_mfma_f32_16x16x32_f16(p, wa[1][f], acc1, 0, 0, 0);
    }
    // h1 -> LDS (reuse stage: all stage reads complete before these writes)
    f16* __restrict__ hb = stg;
    #pragma unroll
    for (int r = 0; r < 4; ++r) {
        const int row = 4 * q + r;
        hb[row * RS + m]      = (f16)fmaxf(acc0[r], 0.0f);
        hb[row * RS + 16 + m] = (f16)fmaxf(acc1[r], 0.0f);
    }

    // ---- Phase B: L2
    const f16x8 w2a = blobL[512 + lane], w2b = blobL[576 + lane];
    const f16x8 a2 = *(const f16x8*)(hb + m * RS + q * 8);
    f32x4 c0 = {b2a, b2a, b2a, b2a};
    f32x4 c1 = {b2b, b2b, b2b, b2b};
    c0 = __builtin_amdgcn_mfma_f32_16x16x32_f16(a2, w2a, c0, 0, 0, 0);
    c1 = __builtin_amdgcn_mfma_f32_16x16x32_f16(a2, w2b, c1, 0, 0, 0);
    #pragma unroll
    for (int r = 0; r < 4; ++r) {
        const int row = 4 * q + r;
        hb[row * RS + m]      = (f16)fmaxf(c0[r], 0.0f);
        hb[row * RS + 16 + m] = (f16)fmaxf(c1[r], 0.0f);
    }

    // ---- Phase C: L3
    const f16x8 w3a = blobL[640 + lane], w3b = blobL[704 + lane];
    const f16x8 a3 = *(const f16x8*)(hb + m * RS + q * 8);
    f32x4 d0 = {b3a, b3a, b3a, b3a};
    f32x4 d1 = {b3b, b3b, b3b, b3b};
    d0 = __builtin_amdgcn_mfma_f32_16x16x32_f16(a3, w3a, d0, 0, 0, 0);
    d1 = __builtin_amdgcn_mfma_f32_16x16x32_f16(a3, w3b, d1, 0, 0, 0);

    // ---- Phase D: L4 directly on C-layout + cross-m shuffle reduce + sigmoid
    float zr[4];
    #pragma unroll
    for (int r = 0; r < 4; ++r)
        zr[r] = fmaxf(d0[r], 0.0f) * w4a + fmaxf(d1[r], 0.0f) * w4b;
    #pragma unroll
    for (int dd = 1; dd < 16; dd <<= 1)
        #pragma unroll
        for (int r = 0; r < 4; ++r)
            zr[r] += __shfl_xor(zr[r], dd, 64);
    if (m == 0) {
        #pragma unroll
        for (int r = 0; r < 4; ++r) {
            const int e = waveBase + 4 * q + r;
            if (e < E) out[e] = 1.0f / (1.0f + __expf(-(zr[r] + b4v)));
        }
    }
}

extern "C" void kernel_launch(void* const* d_in, const int* in_sizes, int n_in,
                              void* d_out, int out_size, void* d_ws, size_t ws_size,
                              hipStream_t stream)
{
    const float* drug  = (const float*)d_in[0];
    // d_in[1] (cell_hidden_out), d_in[3] (proj_W), d_in[4] (proj_b): dead code
    const int*   edges = (const int*)d_in[2];
    const float* W1 = (const float*)d_in[5];
    const float* b1 = (const float*)d_in[6];
    const float* W2 = (const float*)d_in[7];
    const float* b2 = (const float*)d_in[8];
    const float* W3 = (const float*)d_in[9];
    const float* b3 = (const float*)d_in[10];
    const float* W4 = (const float*)d_in[11];
    const float* b4 = (const float*)d_in[12];
    float* out = (float*)d_out;
    f16*   tab = (f16*)d_ws;   // [0,1MB): f16 table; [1MB,+12KB): weight blob

    const int E = in_sizes[2] / 4;

    const int labelBlocks = (E + 255) / 256;       // 1954: covers table (512) too
    hipLaunchKernelGGL(synergy_prepass, dim3(labelBlocks + 1), dim3(256), 0, stream,
                       drug, edges, W1, W2, W3, tab, out, E, labelBlocks);
    hipLaunchKernelGGL(synergy_main, dim3((E + 63) / 64), dim3(256), 0, stream,
                       tab, edges, W4, b1, b2, b3, b4, out, E);
}

// Round 7
// 125.936 us; speedup vs baseline: 1.5421x; 1.0794x over previous
//
#include <hip/hip_runtime.h>
#include <stdint.h>

#define DD 128                 // drug feature dim
#define HH 32                  // hidden dim
#define RS 40                  // f16 per h-row (80 B): conflict-free b128 column reads
#define TABQ (4096 * DD / 4)   // float4 count of drug table
#define BLOB_OFF (1u << 20)    // weight fragment blob offset inside d_ws (bytes)

typedef _Float16 f16;
typedef _Float16 f16x4 __attribute__((ext_vector_type(4)));
typedef _Float16 f16x8 __attribute__((ext_vector_type(8)));
typedef float    f32x4 __attribute__((ext_vector_type(4)));

#define GL1(p)  ((const __attribute__((address_space(1))) void*)(p))
#define LDS3(p) ((__attribute__((address_space(3))) void*)(p))

// Pre-pass: (a) drug table f32->f16 (blocks 0..511); (b) weight-fragment blob
// (W1/W2/W3 pre-swizzled into MFMA B-fragment lane order) at ws+1MB (block 512).
__global__ __launch_bounds__(256)
void synergy_prepass(const float* __restrict__ drug,
                     const float* __restrict__ W1, const float* __restrict__ W2,
                     const float* __restrict__ W3, f16* __restrict__ tab)
{
    const int tid = threadIdx.x;
    if ((int)blockIdx.x == 512) {
        f16x8* __restrict__ blob16 = (f16x8*)((char*)tab + BLOB_OFF);
        const float4* __restrict__ W1v = (const float4*)W1;
        // W1 -> slots 0..511 : S = (t*4+f)*64 + lane ; frag B[k=8q+j][n=16t+m]=W1[n][k]
        #pragma unroll
        for (int p = 0; p < 2; ++p) {
            const int S = p * 256 + tid;
            const int t = S >> 8, f = (S >> 6) & 3, l = S & 63;
            const int mm = l & 15, qq = l >> 4;
            const int c4 = (t * 16 + mm) * (DD / 4) + f * 8 + qq * 2;
            const float4 w0 = W1v[c4], w1 = W1v[c4 + 1];
            f16x8 r;
            r[0]=(f16)w0.x; r[1]=(f16)w0.y; r[2]=(f16)w0.z; r[3]=(f16)w0.w;
            r[4]=(f16)w1.x; r[5]=(f16)w1.y; r[6]=(f16)w1.z; r[7]=(f16)w1.w;
            blob16[S] = r;
        }
        // W2 -> slots 512..639 ; W3 -> slots 640..767
        {
            const int B = tid & 127;
            const int t = B >> 6, l = B & 63;
            const int mm = l & 15, qq = l >> 4;
            const int c4 = (t * 16 + mm) * (HH / 4) + qq * 2;
            const float4* __restrict__ src = (tid < 128) ? (const float4*)W2 : (const float4*)W3;
            const float4 w0 = src[c4], w1 = src[c4 + 1];
            f16x8 r;
            r[0]=(f16)w0.x; r[1]=(f16)w0.y; r[2]=(f16)w0.z; r[3]=(f16)w0.w;
            r[4]=(f16)w1.x; r[5]=(f16)w1.y; r[6]=(f16)w1.z; r[7]=(f16)w1.w;
            blob16[512 + (tid & 128) + B] = r;
        }
        return;
    }
    const int i = blockIdx.x * 256 + tid;
    if (i < TABQ) {
        const float4 v = ((const float4*)drug)[i];
        f16x4 h;
        h[0]=(f16)v.x; h[1]=(f16)v.y; h[2]=(f16)v.z; h[3]=(f16)v.w;
        ((f16x4*)tab)[i] = h;
    }
}

// Main: BARRIER-FREE. Each wave owns 16 edges, fully independent:
//   weights: per-wave global b128 loads from pre-swizzled blob (L2 broadcast)
//   edges:   one coalesced int4 load + 12 shuffles
//   gather:  12 global_load_lds DMAs (48 rows x 256B, rotation swizzle), 0 VGPR
//   compute: 4 layers on MFMA f16 16x16x32; L4 via shuffle-reduce.
// LDS = stage only (48KB/block) -> 3 blocks/CU, 12 waves/CU.
__global__ __launch_bounds__(256, 3)
void synergy_main(const f16* __restrict__ tab, const int* __restrict__ edges,
                  const float* __restrict__ W4, const float* __restrict__ b1,
                  const float* __restrict__ b2, const float* __restrict__ b3,
                  const float* __restrict__ b4, float* __restrict__ out, int E)
{
    __shared__ __align__(16) f16 stage[4][6144];     // 12288 B per wave: 48 rows x 256B

    const int tid  = threadIdx.x;
    const int wave = tid >> 6;
    const int lane = tid & 63;
    const int m    = lane & 15;    // MFMA row / staging slot-in-row
    const int q    = lane >> 4;    // MFMA quad / staging row-in-group

    const int waveBase = blockIdx.x * 64 + wave * 16;
    const char* __restrict__ tabB = (const char*)tab;

    // ---- weight/bias loads first: latency hides under the edge-index chain
    const f16x8* __restrict__ blobG = (const f16x8*)(tabB + BLOB_OFF);
    f16x8 wa[2][4];
    #pragma unroll
    for (int t = 0; t < 2; ++t)
        #pragma unroll
        for (int f = 0; f < 4; ++f)
            wa[t][f] = blobG[(t * 4 + f) * 64 + lane];
    const f16x8 w2a = blobG[512 + lane], w2b = blobG[576 + lane];
    const f16x8 w3a = blobG[640 + lane], w3b = blobG[704 + lane];
    const float b1a = b1[m], b1b = b1[16 + m];
    const float b2a = b2[m], b2b = b2[16 + m];
    const float b3a = b3[m], b3b = b3[16 + m];
    const float w4a = W4[m], w4b = W4[16 + m];
    const float b4v = b4[0];

    // ---- edge indices: one coalesced int4 (lanes 0..15 hold the 16 edges)
    int eL = waveBase + m;
    eL = (eL < E) ? eL : (E - 1);
    const int4 ed = ((const int4*)edges)[eL];

    // label pass-through from the same register (fire-and-forget store)
    if (lane < 16 && waveBase + lane < E)
        out[E + waveBase + lane] = (float)ed.w;

    // distribute row byte-offsets: rowb[t*4+g] = 256 * drug_idx(table t, edge 4g+q)
    int rowb[12];
    #pragma unroll
    for (int g = 0; g < 4; ++g) {
        const int src = 4 * g + q;
        rowb[0 * 4 + g] = __shfl(ed.x, src, 64) << 8;
        rowb[1 * 4 + g] = __shfl(ed.y, src, 64) << 8;
        rowb[2 * 4 + g] = __shfl(ed.z, src, 64) << 8;
    }

    // ---- gather DMA: 12 instrs, each stages 4 full rows (rotation swizzle:
    //      row e stores seg (j+e)&15 at slot j -> conflict-clean readback)
    f16* __restrict__ stg = stage[wave];
    #pragma unroll
    for (int t = 0; t < 3; ++t)
        #pragma unroll
        for (int g = 0; g < 4; ++g) {
            const int seg = (m + 4 * g + q) & 15;
            __builtin_amdgcn_global_load_lds(
                GL1(tabB + (size_t)(rowb[t * 4 + g] + (seg << 4))),
                LDS3((char*)stg + (t * 16 + 4 * g) * 256), 16, 0, 0);
        }
    __builtin_amdgcn_sched_barrier(0);
    __builtin_amdgcn_s_waitcnt(0x0F70);       // vmcnt(0): DMAs + weights landed
    __builtin_amdgcn_sched_barrier(0);

    // ---- Phase A: L1 (8 MFMAs, K=128)
    f32x4 acc0 = {b1a, b1a, b1a, b1a};
    f32x4 acc1 = {b1b, b1b, b1b, b1b};
    #pragma unroll
    for (int f = 0; f < 4; ++f) {
        const int slot = (((f * 4 + q) - m) & 15) << 3;     // f16 offset of 16B seg
        const f16x8 v0 = *(const f16x8*)(stg + (0 * 16 + m) * 128 + slot);
        const f16x8 v1 = *(const f16x8*)(stg + (1 * 16 + m) * 128 + slot);
        const f16x8 v2 = *(const f16x8*)(stg + (2 * 16 + m) * 128 + slot);
        const f16x8 p = v0 * v1 * v2;                       // v_pk_mul_f16 -> A-frag
        acc0 = __builtin_amdgcn_mfma_f32_16x16x32_f16(p, wa[0][f], acc0, 0, 0, 0);
        acc1 = __builtin_amdgcn_mfma_f32_16x16x32_f16(p, wa[1][f], acc1, 0, 0, 0);
    }
    // h1 -> LDS (reuse stage: all stage reads complete before these writes)
    f16* __restrict__ hb = stg;
    #pragma unroll
    for (int r = 0; r < 4; ++r) {
        const int row = 4 * q + r;
        hb[row * RS + m]      = (f16)fmaxf(acc0[r], 0.0f);
        hb[row * RS + 16 + m] = (f16)fmaxf(acc1[r], 0.0f);
    }

    // ---- Phase B: L2
    const f16x8 a2 = *(const f16x8*)(hb + m * RS + q * 8);
    f32x4 c0 = {b2a, b2a, b2a, b2a};
    f32x4 c1 = {b2b, b2b, b2b, b2b};
    c0 = __builtin_amdgcn_mfma_f32_16x16x32_f16(a2, w2a, c0, 0, 0, 0);
    c1 = __builtin_amdgcn_mfma_f32_16x16x32_f16(a2, w2b, c1, 0, 0, 0);
    #pragma unroll
    for (int r = 0; r < 4; ++r) {
        const int row = 4 * q + r;
        hb[row * RS + m]      = (f16)fmaxf(c0[r], 0.0f);
        hb[row * RS + 16 + m] = (f16)fmaxf(c1[r], 0.0f);
    }

    // ---- Phase C: L3
    const f16x8 a3 = *(const f16x8*)(hb + m * RS + q * 8);
    f32x4 d0 = {b3a, b3a, b3a, b3a};
    f32x4 d1 = {b3b, b3b, b3b, b3b};
    d0 = __builtin_amdgcn_mfma_f32_16x16x32_f16(a3, w3a, d0, 0, 0, 0);
    d1 = __builtin_amdgcn_mfma_f32_16x16x32_f16(a3, w3b, d1, 0, 0, 0);

    // ---- Phase D: L4 directly on C-layout + cross-m shuffle reduce + sigmoid
    float zr[4];
    #pragma unroll
    for (int r = 0; r < 4; ++r)
        zr[r] = fmaxf(d0[r], 0.0f) * w4a + fmaxf(d1[r], 0.0f) * w4b;
    #pragma unroll
    for (int dd = 1; dd < 16; dd <<= 1)
        #pragma unroll
        for (int r = 0; r < 4; ++r)
            zr[r] += __shfl_xor(zr[r], dd, 64);
    if (m == 0) {
        #pragma unroll
        for (int r = 0; r < 4; ++r) {
            const int e = waveBase + 4 * q + r;
            if (e < E) out[e] = 1.0f / (1.0f + __expf(-(zr[r] + b4v)));
        }
    }
}

extern "C" void kernel_launch(void* const* d_in, const int* in_sizes, int n_in,
                              void* d_out, int out_size, void* d_ws, size_t ws_size,
                              hipStream_t stream)
{
    const float* drug  = (const float*)d_in[0];
    // d_in[1] (cell_hidden_out), d_in[3] (proj_W), d_in[4] (proj_b): dead code
    const int*   edges = (const int*)d_in[2];
    const float* W1 = (const float*)d_in[5];
    const float* b1 = (const float*)d_in[6];
    const float* W2 = (const float*)d_in[7];
    const float* b2 = (const float*)d_in[8];
    const float* W3 = (const float*)d_in[9];
    const float* b3 = (const float*)d_in[10];
    const float* W4 = (const float*)d_in[11];
    const float* b4 = (const float*)d_in[12];
    float* out = (float*)d_out;
    f16*   tab = (f16*)d_ws;   // [0,1MB): f16 table; [1MB,+12KB): weight blob

    const int E = in_sizes[2] / 4;

    hipLaunchKernelGGL(synergy_prepass, dim3(513), dim3(256), 0, stream,
                       drug, W1, W2, W3, tab);
    hipLaunchKernelGGL(synergy_main, dim3((E + 63) / 64), dim3(256), 0, stream,
                       tab, edges, W4, b1, b2, b3, b4, out, E);
}

// Round 8
// 123.703 us; speedup vs baseline: 1.5699x; 1.0181x over previous
//
#include <hip/hip_runtime.h>
#include <stdint.h>

#define DD 128                 // drug feature dim
#define HH 32                  // hidden dim
#define RS 36                  // f16 per h-row (72 B): 18m mod 32 distinct -> <=2-way (free)
#define TABQ (4096 * DD / 4)   // float4 count of drug table
#define BLOB_OFF (1u << 20)    // weight fragment blob offset inside d_ws (bytes)

typedef _Float16 f16;
typedef _Float16 f16x4 __attribute__((ext_vector_type(4)));
typedef _Float16 f16x8 __attribute__((ext_vector_type(8)));
typedef float    f32x4 __attribute__((ext_vector_type(4)));

#define GL1(p)  ((const __attribute__((address_space(1))) void*)(p))
#define LDS3(p) ((__attribute__((address_space(3))) void*)(p))

// Pre-pass: (a) drug table f32->f16 (blocks 0..511); (b) weight-fragment blob
// (W1/W2/W3 pre-swizzled into MFMA B-fragment lane order) at ws+1MB (block 512).
__global__ __launch_bounds__(256)
void synergy_prepass(const float* __restrict__ drug,
                     const float* __restrict__ W1, const float* __restrict__ W2,
                     const float* __restrict__ W3, f16* __restrict__ tab)
{
    const int tid = threadIdx.x;
    if ((int)blockIdx.x == 512) {
        f16x8* __restrict__ blob16 = (f16x8*)((char*)tab + BLOB_OFF);
        const float4* __restrict__ W1v = (const float4*)W1;
        #pragma unroll
        for (int p = 0; p < 2; ++p) {
            const int S = p * 256 + tid;
            const int t = S >> 8, f = (S >> 6) & 3, l = S & 63;
            const int mm = l & 15, qq = l >> 4;
            const int c4 = (t * 16 + mm) * (DD / 4) + f * 8 + qq * 2;
            const float4 w0 = W1v[c4], w1 = W1v[c4 + 1];
            f16x8 r;
            r[0]=(f16)w0.x; r[1]=(f16)w0.y; r[2]=(f16)w0.z; r[3]=(f16)w0.w;
            r[4]=(f16)w1.x; r[5]=(f16)w1.y; r[6]=(f16)w1.z; r[7]=(f16)w1.w;
            blob16[S] = r;
        }
        {
            const int B = tid & 127;
            const int t = B >> 6, l = B & 63;
            const int mm = l & 15, qq = l >> 4;
            const int c4 = (t * 16 + mm) * (HH / 4) + qq * 2;
            const float4* __restrict__ src = (tid < 128) ? (const float4*)W2 : (const float4*)W3;
            const float4 w0 = src[c4], w1 = src[c4 + 1];
            f16x8 r;
            r[0]=(f16)w0.x; r[1]=(f16)w0.y; r[2]=(f16)w0.z; r[3]=(f16)w0.w;
            r[4]=(f16)w1.x; r[5]=(f16)w1.y; r[6]=(f16)w1.z; r[7]=(f16)w1.w;
            blob16[512 + (tid & 128) + B] = r;
        }
        return;
    }
    const int i = blockIdx.x * 256 + tid;
    if (i < TABQ) {
        const float4 v = ((const float4*)drug)[i];
        f16x4 h;
        h[0]=(f16)v.x; h[1]=(f16)v.y; h[2]=(f16)v.z; h[3]=(f16)v.w;
        ((f16x4*)tab)[i] = h;
    }
}

// Main: PERSISTENT, software-pipelined. Each wave grid-strides over 16-edge
// groups. Weights/biases load once per wave. Per iteration: wait DMAs ->
// phase A (consume stage) -> prefetch edges 2 groups ahead -> issue next
// group's 12 DMAs (stage reuse, WAR-safe post-consumption) -> phases B-D
// cover the DMA flight. h-buffer is a separate region so stage can be DMA'd
// while h lives. Barrier-free.
__global__ __launch_bounds__(256, 3)
void synergy_main(const f16* __restrict__ tab, const int* __restrict__ edges,
                  const float* __restrict__ W4, const float* __restrict__ b1,
                  const float* __restrict__ b2, const float* __restrict__ b3,
                  const float* __restrict__ b4, float* __restrict__ out,
                  int E, int NG)
{
    __shared__ __align__(16) f16 stage[4][6144];   // 48 KiB: 48 rows x 256 B per wave
    __shared__ __align__(16) f16 hbuf[4][16 * RS]; // 4.5 KiB: h rows per wave

    const int tid  = threadIdx.x;
    const int wave = tid >> 6;
    const int lane = tid & 63;
    const int m    = lane & 15;    // MFMA row / staging slot-in-row
    const int q    = lane >> 4;    // MFMA quad / staging row-in-group

    const int WSTR = (int)gridDim.x * 4;
    int g = (int)blockIdx.x * 4 + wave;
    if (g >= NG) return;

    const char* __restrict__ tabB   = (const char*)tab;
    const int4* __restrict__ edges4 = (const int4*)edges;

    // ---- per-wave constants: weights (pre-swizzled blob, L2 broadcast), biases
    const f16x8* __restrict__ blobG = (const f16x8*)(tabB + BLOB_OFF);
    f16x8 wa[2][4];
    #pragma unroll
    for (int t = 0; t < 2; ++t)
        #pragma unroll
        for (int f = 0; f < 4; ++f)
            wa[t][f] = blobG[(t * 4 + f) * 64 + lane];
    const f16x8 w2a = blobG[512 + lane], w2b = blobG[576 + lane];
    const f16x8 w3a = blobG[640 + lane], w3b = blobG[704 + lane];
    const float b1a = b1[m], b1b = b1[16 + m];
    const float b2a = b2[m], b2b = b2[16 + m];
    const float b3a = b3[m], b3b = b3[16 + m];
    const float w4a = W4[m], w4b = W4[16 + m];
    const float b4v = b4[0];

    f16* __restrict__ stg = stage[wave];
    f16* __restrict__ hb  = hbuf[wave];

    // Rotation-swizzled gather: row e_t stores seg (slot+e_t)&15 at slot
    auto issue_dma = [&](const int4 ed) {
        #pragma unroll
        for (int gg = 0; gg < 4; ++gg) {
            const int src   = 4 * gg + q;
            const int seg16 = ((m + src) & 15) << 4;
            const int rx = __shfl(ed.x, src, 64) << 8;
            __builtin_amdgcn_global_load_lds(GL1(tabB + (size_t)(rx + seg16)),
                LDS3((char*)stg + (0 * 16 + 4 * gg) * 256), 16, 0, 0);
            const int ry = __shfl(ed.y, src, 64) << 8;
            __builtin_amdgcn_global_load_lds(GL1(tabB + (size_t)(ry + seg16)),
                LDS3((char*)stg + (1 * 16 + 4 * gg) * 256), 16, 0, 0);
            const int rz = __shfl(ed.z, src, 64) << 8;
            __builtin_amdgcn_global_load_lds(GL1(tabB + (size_t)(rz + seg16)),
                LDS3((char*)stg + (2 * 16 + 4 * gg) * 256), 16, 0, 0);
        }
    };
    auto load_ed = [&](int gg) -> int4 {
        int e = (gg << 4) + m;
        e = (e < E) ? e : (E - 1);
        return edges4[e];
    };

    // ---- prologue: DMA group g; prefetch edges for group g+WSTR
    int4 ed_cur = load_ed(g);
    issue_dma(ed_cur);
    int gn = g + WSTR;
    int4 ed_nxt = load_ed((gn < NG) ? gn : g);

    for (;;) {
        __builtin_amdgcn_sched_barrier(0);
        __builtin_amdgcn_s_waitcnt(0x0F70);     // vmcnt(0): stage DMAs landed
        __builtin_amdgcn_sched_barrier(0);

        // ---- Phase A: L1 (8 MFMAs, K=128); consumes stage
        f32x4 acc0 = {b1a, b1a, b1a, b1a};
        f32x4 acc1 = {b1b, b1b, b1b, b1b};
        #pragma unroll
        for (int f = 0; f < 4; ++f) {
            const int slot = (((f * 4 + q) - m) & 15) << 3;
            const f16x8 v0 = *(const f16x8*)(stg + (0 * 16 + m) * 128 + slot);
            const f16x8 v1 = *(const f16x8*)(stg + (1 * 16 + m) * 128 + slot);
            const f16x8 v2 = *(const f16x8*)(stg + (2 * 16 + m) * 128 + slot);
            const f16x8 p = v0 * v1 * v2;
            acc0 = __builtin_amdgcn_mfma_f32_16x16x32_f16(p, wa[0][f], acc0, 0, 0, 0);
            acc1 = __builtin_amdgcn_mfma_f32_16x16x32_f16(p, wa[1][f], acc1, 0, 0, 0);
        }
        #pragma unroll
        for (int r = 0; r < 4; ++r) {
            const int row = 4 * q + r;
            hb[row * RS + m]      = (f16)fmaxf(acc0[r], 0.0f);
            hb[row * RS + 16 + m] = (f16)fmaxf(acc1[r], 0.0f);
        }

        // ---- prefetch edges two groups ahead (pure register, covers HBM latency)
        const int gf = gn + WSTR;
        const int4 ed_fut = load_ed((gf < NG) ? gf : g);

        // ---- issue next group's DMAs (stage reads fully consumed by MFMAs above)
        if (gn < NG) {
            __builtin_amdgcn_sched_barrier(0);
            issue_dma(ed_nxt);
            __builtin_amdgcn_sched_barrier(0);
        }

        // ---- Phase B: L2 (covers DMA flight)
        {
            const f16x8 a2 = *(const f16x8*)(hb + m * RS + q * 8);
            f32x4 c0 = {b2a, b2a, b2a, b2a};
            f32x4 c1 = {b2b, b2b, b2b, b2b};
            c0 = __builtin_amdgcn_mfma_f32_16x16x32_f16(a2, w2a, c0, 0, 0, 0);
            c1 = __builtin_amdgcn_mfma_f32_16x16x32_f16(a2, w2b, c1, 0, 0, 0);
            #pragma unroll
            for (int r = 0; r < 4; ++r) {
                const int row = 4 * q + r;
                hb[row * RS + m]      = (f16)fmaxf(c0[r], 0.0f);
                hb[row * RS + 16 + m] = (f16)fmaxf(c1[r], 0.0f);
            }
        }

        // ---- Phase C: L3
        f32x4 d0 = {b3a, b3a, b3a, b3a};
        f32x4 d1 = {b3b, b3b, b3b, b3b};
        {
            const f16x8 a3 = *(const f16x8*)(hb + m * RS + q * 8);
            d0 = __builtin_amdgcn_mfma_f32_16x16x32_f16(a3, w3a, d0, 0, 0, 0);
            d1 = __builtin_amdgcn_mfma_f32_16x16x32_f16(a3, w3b, d1, 0, 0, 0);
        }

        // ---- Phase D: L4 on C-layout + cross-m shuffle reduce + sigmoid + stores
        float zr[4];
        #pragma unroll
        for (int r = 0; r < 4; ++r)
            zr[r] = fmaxf(d0[r], 0.0f) * w4a + fmaxf(d1[r], 0.0f) * w4b;
        #pragma unroll
        for (int dd = 1; dd < 16; dd <<= 1)
            #pragma unroll
            for (int r = 0; r < 4; ++r)
                zr[r] += __shfl_xor(zr[r], dd, 64);
        if (m == 0) {
            const int e0 = (g << 4) + 4 * q;
            float4 res;
            res.x = 1.0f / (1.0f + __expf(-(zr[0] + b4v)));
            res.y = 1.0f / (1.0f + __expf(-(zr[1] + b4v)));
            res.z = 1.0f / (1.0f + __expf(-(zr[2] + b4v)));
            res.w = 1.0f / (1.0f + __expf(-(zr[3] + b4v)));
            if (e0 + 3 < E) *(float4*)(out + e0) = res;
            else {
                if (e0 + 0 < E) out[e0 + 0] = res.x;
                if (e0 + 1 < E) out[e0 + 1] = res.y;
                if (e0 + 2 < E) out[e0 + 2] = res.z;
                if (e0 + 3 < E) out[e0 + 3] = res.w;
            }
        }
        const int eL = (g << 4) + lane;
        if (lane < 16 && eL < E) out[E + eL] = (float)ed_cur.w;

        if (gn >= NG) break;
        g = gn; gn = gf; ed_cur = ed_nxt; ed_nxt = ed_fut;
    }
}

extern "C" void kernel_launch(void* const* d_in, const int* in_sizes, int n_in,
                              void* d_out, int out_size, void* d_ws, size_t ws_size,
                              hipStream_t stream)
{
    const float* drug  = (const float*)d_in[0];
    // d_in[1] (cell_hidden_out), d_in[3] (proj_W), d_in[4] (proj_b): dead code
    const int*   edges = (const int*)d_in[2];
    const float* W1 = (const float*)d_in[5];
    const float* b1 = (const float*)d_in[6];
    const float* W2 = (const float*)d_in[7];
    const float* b2 = (const float*)d_in[8];
    const float* W3 = (const float*)d_in[9];
    const float* b3 = (const float*)d_in[10];
    const float* W4 = (const float*)d_in[11];
    const float* b4 = (const float*)d_in[12];
    float* out = (float*)d_out;
    f16*   tab = (f16*)d_ws;   // [0,1MB): f16 table; [1MB,+12KB): weight blob

    const int E  = in_sizes[2] / 4;
    const int NG = (E + 15) / 16;

    hipLaunchKernelGGL(synergy_prepass, dim3(513), dim3(256), 0, stream,
                       drug, W1, W2, W3, tab);
    int blocks = (NG + 3) / 4;
    if (blocks > 768) blocks = 768;          // 3 blocks/CU x 256 CUs
    hipLaunchKernelGGL(synergy_main, dim3(blocks), dim3(256), 0, stream,
                       tab, edges, W4, b1, b2, b3, b4, out, E, NG);
}

// Round 9
// 121.714 us; speedup vs baseline: 1.5956x; 1.0163x over previous
//
#include <hip/hip_runtime.h>
#include <stdint.h>

#define DD 128                 // drug feature dim
#define HH 32                  // hidden dim
#define RS 36                  // f16 per h-row (72 B): 18m mod 32 distinct -> <=2-way (free)
#define TABQ (4096 * DD / 4)   // float4 count of drug table
#define BLOB_OFF (1u << 20)    // weight fragment blob offset inside d_ws (bytes)

typedef _Float16 f16;
typedef _Float16 f16x4 __attribute__((ext_vector_type(4)));
typedef _Float16 f16x8 __attribute__((ext_vector_type(8)));
typedef float    f32x4 __attribute__((ext_vector_type(4)));

#define GL1(p)  ((const __attribute__((address_space(1))) void*)(p))
#define LDS3(p) ((__attribute__((address_space(3))) void*)(p))

// Pre-pass: (a) drug table f32->f16 (blocks 0..511); (b) weight-fragment blob
// at ws+1MB (block 512): W1 slots 0..511, W2 512..639, W3 640..767,
// W4-column-fragment 768..831 (lane m==0 holds W4[8q+j], else 0).
__global__ __launch_bounds__(256)
void synergy_prepass(const float* __restrict__ drug,
                     const float* __restrict__ W1, const float* __restrict__ W2,
                     const float* __restrict__ W3, const float* __restrict__ W4,
                     f16* __restrict__ tab)
{
    const int tid = threadIdx.x;
    if ((int)blockIdx.x == 512) {
        f16x8* __restrict__ blob16 = (f16x8*)((char*)tab + BLOB_OFF);
        const float4* __restrict__ W1v = (const float4*)W1;
        #pragma unroll
        for (int p = 0; p < 2; ++p) {
            const int S = p * 256 + tid;
            const int t = S >> 8, f = (S >> 6) & 3, l = S & 63;
            const int mm = l & 15, qq = l >> 4;
            const int c4 = (t * 16 + mm) * (DD / 4) + f * 8 + qq * 2;
            const float4 w0 = W1v[c4], w1 = W1v[c4 + 1];
            f16x8 r;
            r[0]=(f16)w0.x; r[1]=(f16)w0.y; r[2]=(f16)w0.z; r[3]=(f16)w0.w;
            r[4]=(f16)w1.x; r[5]=(f16)w1.y; r[6]=(f16)w1.z; r[7]=(f16)w1.w;
            blob16[S] = r;
        }
        {
            const int B = tid & 127;
            const int t = B >> 6, l = B & 63;
            const int mm = l & 15, qq = l >> 4;
            const int c4 = (t * 16 + mm) * (HH / 4) + qq * 2;
            const float4* __restrict__ src = (tid < 128) ? (const float4*)W2 : (const float4*)W3;
            const float4 w0 = src[c4], w1 = src[c4 + 1];
            f16x8 r;
            r[0]=(f16)w0.x; r[1]=(f16)w0.y; r[2]=(f16)w0.z; r[3]=(f16)w0.w;
            r[4]=(f16)w1.x; r[5]=(f16)w1.y; r[6]=(f16)w1.z; r[7]=(f16)w1.w;
            blob16[512 + (tid & 128) + B] = r;
        }
        if (tid < 64) {                         // W4 column fragment
            const int mm = tid & 15, qq = tid >> 4;
            f16x8 r;
            #pragma unroll
            for (int j = 0; j < 8; ++j)
                r[j] = (mm == 0) ? (f16)W4[qq * 8 + j] : (f16)0.0f;
            blob16[768 + tid] = r;
        }
        return;
    }
    const int i = blockIdx.x * 256 + tid;
    if (i < TABQ) {
        const float4 v = ((const float4*)drug)[i];
        f16x4 h;
        h[0]=(f16)v.x; h[1]=(f16)v.y; h[2]=(f16)v.z; h[3]=(f16)v.w;
        ((f16x4*)tab)[i] = h;
    }
}

// Main: PERSISTENT, TAIL-ISSUE pipeline. Per iteration: loop-top vmcnt(0)
// (sole drain point) -> phases A-D (all LDS traffic here) -> stores -> edge
// shuffles -> issue next group's 12 DMAs LAST -> loop. The DMA flight is
// covered by the other resident waves; no LDS read sits between issue and
// the top wait, so the legalizer cannot insert mid-loop drains. L4 is an
// MFMA with a zero-padded W4 column fragment -> no bpermute reduce.
__global__ __launch_bounds__(256, 3)
void synergy_main(const f16* __restrict__ tab, const int* __restrict__ edges,
                  const float* __restrict__ b1, const float* __restrict__ b2,
                  const float* __restrict__ b3, const float* __restrict__ b4,
                  float* __restrict__ out, int E, int NG)
{
    __shared__ __align__(16) f16 stage[4][6144];   // 48 KiB: 48 rows x 256 B per wave
    __shared__ __align__(16) f16 hbuf[4][16 * RS]; // 4.5 KiB per block

    const int tid  = threadIdx.x;
    const int wave = tid >> 6;
    const int lane = tid & 63;
    const int m    = lane & 15;
    const int q    = lane >> 4;

    const int WSTR = (int)gridDim.x * 4;
    int g = (int)blockIdx.x * 4 + wave;
    if (g >= NG) return;

    const char* __restrict__ tabB   = (const char*)tab;
    const int4* __restrict__ edges4 = (const int4*)edges;

    // ---- per-wave constants: weights (pre-swizzled blob, L2 broadcast), biases
    const f16x8* __restrict__ blobG = (const f16x8*)(tabB + BLOB_OFF);
    f16x8 wa[2][4];
    #pragma unroll
    for (int t = 0; t < 2; ++t)
        #pragma unroll
        for (int f = 0; f < 4; ++f)
            wa[t][f] = blobG[(t * 4 + f) * 64 + lane];
    const f16x8 w2a = blobG[512 + lane], w2b = blobG[576 + lane];
    const f16x8 w3a = blobG[640 + lane], w3b = blobG[704 + lane];
    const f16x8 wf4 = blobG[768 + lane];
    const float b1a = b1[m], b1b = b1[16 + m];
    const float b2a = b2[m], b2b = b2[16 + m];
    const float b3a = b3[m], b3b = b3[16 + m];
    const float b4v = b4[0];

    f16* __restrict__ stg = stage[wave];
    f16* __restrict__ hb  = hbuf[wave];

    auto load_ed = [&](int gg) -> int4 {
        int e = (gg << 4) + m;
        e = (e < E) ? e : (E - 1);
        return edges4[e];
    };
    // Rotation-swizzled gather: DMA (t,gg) -> lane 16q+m stages row 4gg+q,
    // slot m, fetching global segment (m + 4gg + q) & 15 of that row.
    auto issue_dma = [&](const int4 ed) {
        int rowb[12];
        #pragma unroll
        for (int gg = 0; gg < 4; ++gg) {
            const int src = 4 * gg + q;
            rowb[0 * 4 + gg] = __shfl(ed.x, src, 64) << 8;
            rowb[1 * 4 + gg] = __shfl(ed.y, src, 64) << 8;
            rowb[2 * 4 + gg] = __shfl(ed.z, src, 64) << 8;
        }
        __builtin_amdgcn_sched_barrier(0);
        #pragma unroll
        for (int t = 0; t < 3; ++t)
            #pragma unroll
            for (int gg = 0; gg < 4; ++gg) {
                const int seg16 = ((m + 4 * gg + q) & 15) << 4;
                __builtin_amdgcn_global_load_lds(
                    GL1(tabB + (size_t)(rowb[t * 4 + gg] + seg16)),
                    LDS3((char*)stg + (t * 16 + 4 * gg) * 256), 16, 0, 0);
            }
    };

    // ---- prologue
    int4 ed_cur = load_ed(g);
    issue_dma(ed_cur);
    int gn = g + WSTR;
    int4 ed_nxt = load_ed((gn < NG) ? gn : g);

    for (;;) {
        __builtin_amdgcn_s_waitcnt(0x0F70);     // vmcnt(0): stage DMAs landed
        __builtin_amdgcn_sched_barrier(0);

        // ---- Phase A: L1 (8 MFMAs, K=128); consumes stage
        f32x4 acc0 = {b1a, b1a, b1a, b1a};
        f32x4 acc1 = {b1b, b1b, b1b, b1b};
        #pragma unroll
        for (int f = 0; f < 4; ++f) {
            const int slot = (((f * 4 + q) - m) & 15) << 3;
            const f16x8 v0 = *(const f16x8*)(stg + (0 * 16 + m) * 128 + slot);
            const f16x8 v1 = *(const f16x8*)(stg + (1 * 16 + m) * 128 + slot);
            const f16x8 v2 = *(const f16x8*)(stg + (2 * 16 + m) * 128 + slot);
            const f16x8 p = v0 * v1 * v2;
            acc0 = __builtin_amdgcn_mfma_f32_16x16x32_f16(p, wa[0][f], acc0, 0, 0, 0);
            acc1 = __builtin_amdgcn_mfma_f32_16x16x32_f16(p, wa[1][f], acc1, 0, 0, 0);
        }
        #pragma unroll
        for (int r = 0; r < 4; ++r) {
            const int row = 4 * q + r;
            hb[row * RS + m]      = (f16)fmaxf(acc0[r], 0.0f);
            hb[row * RS + 16 + m] = (f16)fmaxf(acc1[r], 0.0f);
        }

        // ---- prefetch edges two groups ahead (register; drained next top-wait)
        const int gf = gn + WSTR;
        const int4 ed_fut = load_ed((gf < NG) ? gf : g);

        // ---- Phase B: L2
        {
            const f16x8 a2 = *(const f16x8*)(hb + m * RS + q * 8);
            f32x4 c0 = {b2a, b2a, b2a, b2a};
            f32x4 c1 = {b2b, b2b, b2b, b2b};
            c0 = __builtin_amdgcn_mfma_f32_16x16x32_f16(a2, w2a, c0, 0, 0, 0);
            c1 = __builtin_amdgcn_mfma_f32_16x16x32_f16(a2, w2b, c1, 0, 0, 0);
            #pragma unroll
            for (int r = 0; r < 4; ++r) {
                const int row = 4 * q + r;
                hb[row * RS + m]      = (f16)fmaxf(c0[r], 0.0f);
                hb[row * RS + 16 + m] = (f16)fmaxf(c1[r], 0.0f);
            }
        }

        // ---- Phase C: L3 (h3 back to LDS for L4's A-operand)
        {
            const f16x8 a3 = *(const f16x8*)(hb + m * RS + q * 8);
            f32x4 d0 = {b3a, b3a, b3a, b3a};
            f32x4 d1 = {b3b, b3b, b3b, b3b};
            d0 = __builtin_amdgcn_mfma_f32_16x16x32_f16(a3, w3a, d0, 0, 0, 0);
            d1 = __builtin_amdgcn_mfma_f32_16x16x32_f16(a3, w3b, d1, 0, 0, 0);
            #pragma unroll
            for (int r = 0; r < 4; ++r) {
                const int row = 4 * q + r;
                hb[row * RS + m]      = (f16)fmaxf(d0[r], 0.0f);
                hb[row * RS + 16 + m] = (f16)fmaxf(d1[r], 0.0f);
            }
        }

        // ---- Phase D: L4 as MFMA vs zero-padded W4 column; col 0 = result
        {
            const f16x8 a4 = *(const f16x8*)(hb + m * RS + q * 8);
            f32x4 z = {b4v, b4v, b4v, b4v};
            z = __builtin_amdgcn_mfma_f32_16x16x32_f16(a4, wf4, z, 0, 0, 0);
            if (m == 0) {                        // lanes 0,16,32,48: rows 4q..4q+3
                const int e0 = (g << 4) + 4 * q;
                float4 res;
                res.x = 1.0f / (1.0f + __expf(-z[0]));
                res.y = 1.0f / (1.0f + __expf(-z[1]));
                res.z = 1.0f / (1.0f + __expf(-z[2]));
                res.w = 1.0f / (1.0f + __expf(-z[3]));
                if (e0 + 3 < E) *(float4*)(out + e0) = res;
                else {
                    if (e0 + 0 < E) out[e0 + 0] = res.x;
                    if (e0 + 1 < E) out[e0 + 1] = res.y;
                    if (e0 + 2 < E) out[e0 + 2] = res.z;
                }
            }
        }
        // label pass-through
        const int eL = (g << 4) + lane;
        if (lane < 16 && eL < E) out[E + eL] = (float)ed_cur.w;

        // ---- TAIL: issue next group's DMAs (nothing after this reads LDS)
        if (gn >= NG) break;
        issue_dma(ed_nxt);
        g = gn; gn = gf; ed_cur = ed_nxt; ed_nxt = ed_fut;
    }
}

extern "C" void kernel_launch(void* const* d_in, const int* in_sizes, int n_in,
                              void* d_out, int out_size, void* d_ws, size_t ws_size,
                              hipStream_t stream)
{
    const float* drug  = (const float*)d_in[0];
    // d_in[1] (cell_hidden_out), d_in[3] (proj_W), d_in[4] (proj_b): dead code
    const int*   edges = (const int*)d_in[2];
    const float* W1 = (const float*)d_in[5];
    const float* b1 = (const float*)d_in[6];
    const float* W2 = (const float*)d_in[7];
    const float* b2 = (const float*)d_in[8];
    const float* W3 = (const float*)d_in[9];
    const float* b3 = (const float*)d_in[10];
    const float* W4 = (const float*)d_in[11];
    const float* b4 = (const float*)d_in[12];
    float* out = (float*)d_out;
    f16*   tab = (f16*)d_ws;   // [0,1MB): f16 table; [1MB,+13KB): weight blob

    const int E  = in_sizes[2] / 4;
    const int NG = (E + 15) / 16;

    hipLaunchKernelGGL(synergy_prepass, dim3(513), dim3(256), 0, stream,
                       drug, W1, W2, W3, W4, tab);
    int blocks = (NG + 3) / 4;
    if (blocks > 768) blocks = 768;          // 3 blocks/CU x 256 CUs
    hipLaunchKernelGGL(synergy_main, dim3(blocks), dim3(256), 0, stream,
                       tab, edges, b1, b2, b3, b4, out, E, NG);
}